// Round 8
// baseline (348.535 us; speedup 1.0000x reference)
//
#include <hip/hip_runtime.h>
#include <hip/hip_bf16.h>
#include <math.h>

typedef __bf16 bf16;
typedef __bf16 bf16x8 __attribute__((ext_vector_type(8)));
typedef float floatx4 __attribute__((ext_vector_type(4)));

#define NT 4096        // B*S tokens
#define DMODEL 1024
#define NHEAD 16
#define DHEAD 64
#define FFDIM 4096

__device__ __forceinline__ void load_lds16(const void* g, void* l) {
    __builtin_amdgcn_global_load_lds(
        (const __attribute__((address_space(1))) void*)g,
        (__attribute__((address_space(3))) void*)l,
        16, 0, 0);
}

__device__ __forceinline__ unsigned short f2bf(float f) {
    bf16 h = (bf16)f;
    return __builtin_bit_cast(unsigned short, h);
}

__device__ __forceinline__ float gelu_f(float v) {
    return 0.5f * v * (1.0f + tanhf(0.7978845608028654f * (v + 0.044715f * v * v * v)));
}

// ---------------------------------------------------------------------------
// cast fp32 -> bf16 for query + all weights; build concat qkv bias
// ---------------------------------------------------------------------------
__global__ __launch_bounds__(256) void cast_kernel(
    const float* __restrict__ q, const float* __restrict__ wq, const float* __restrict__ wk,
    const float* __restrict__ wv, const float* __restrict__ wo, const float* __restrict__ w1,
    const float* __restrict__ w2, const float* __restrict__ bq, const float* __restrict__ bk,
    const float* __restrict__ bv, bf16* __restrict__ xbf, bf16* __restrict__ wqkv,
    bf16* __restrict__ wob, bf16* __restrict__ w1b, bf16* __restrict__ w2b,
    float* __restrict__ bqkv)
{
    int gid = blockIdx.x * 256 + threadIdx.x;
    if (gid < 3072)
        bqkv[gid] = gid < 1024 ? bq[gid] : (gid < 2048 ? bk[gid - 1024] : bv[gid - 2048]);

    const float4* src;
    ushort4* dst;
    int off = gid;
    if (off < 1048576)                  { src = (const float4*)q;  dst = (ushort4*)xbf; }
    else if ((off -= 1048576) < 262144) { src = (const float4*)wq; dst = (ushort4*)wqkv; }
    else if ((off -= 262144) < 262144)  { src = (const float4*)wk; dst = (ushort4*)wqkv + 262144; }
    else if ((off -= 262144) < 262144)  { src = (const float4*)wv; dst = (ushort4*)wqkv + 524288; }
    else if ((off -= 262144) < 262144)  { src = (const float4*)wo; dst = (ushort4*)wob; }
    else if ((off -= 262144) < 1048576) { src = (const float4*)w1; dst = (ushort4*)w1b; }
    else { off -= 1048576;                src = (const float4*)w2; dst = (ushort4*)w2b; }

    float4 v = src[off];
    ushort4 u;
    u.x = f2bf(v.x); u.y = f2bf(v.y); u.z = f2bf(v.z); u.w = f2bf(v.w);
    dst[off] = u;
}

// ---------------------------------------------------------------------------
// GEMM: C[M,N] = A[M,K] * W[N,K]^T + bias.  Tile 128 x TN, BK=64,
// SINGLE-buffered LDS, optional split-K (blockIdx.z -> f32 partial plane).
// Per iter: sync -> ds_read ALL frags -> sync -> issue next tile's
// global_load_lds -> MFMAs (hide load flight under MFMA).
// Staging source addresses XOR-swizzled (ch ^= row&7).
// EPI=0: bf16 = acc+bias | EPI=1: f32 = acc+bias+res | EPI=2: f32 =
// res+gelu(acc+bias) | EPI=3: f32 raw partial plane.
// ---------------------------------------------------------------------------
template <int EPI, int TN, int SPLITK = 1>
__global__ __launch_bounds__(256) void gemm_bt(
    const bf16* __restrict__ A, const bf16* __restrict__ Wt,
    const float* __restrict__ bias, const float* __restrict__ res,
    void* __restrict__ outp, int M, int N, int K)
{
    constexpr int NJ = TN / 32;          // n-frags per wave (4 or 2)
    __shared__ __align__(16) bf16 As[128 * 64];
    __shared__ __align__(16) bf16 Bs[TN * 64];

    const int t = threadIdx.x;
    const int lane = t & 63, wave = t >> 6;
    const int l15 = lane & 15, quad = lane >> 4;
    const int wm = wave & 1, wn = wave >> 1;
    const int m0 = blockIdx.x * 128, n0 = blockIdx.y * TN;
    const int kz = (SPLITK > 1) ? blockIdx.z : 0;
    const int kspan = K / SPLITK;
    const int kstart = kz * kspan;

    floatx4 acc[4][NJ] = {};

    auto issue_loads = [&](int k0) {
        #pragma unroll
        for (int i = 0; i < 4; ++i) {
            int l = t + i * 256;
            int row = l >> 3, ch = (l & 7) ^ (row & 7);
            load_lds16(A + (size_t)(m0 + row) * K + k0 + ch * 8,
                       &As[(size_t)(i * 256 + wave * 64) * 8]);
        }
        #pragma unroll
        for (int i = 0; i < TN / 32; ++i) {
            int l = t + i * 256;
            int row = l >> 3, ch = (l & 7) ^ (row & 7);
            load_lds16(Wt + (size_t)(n0 + row) * K + k0 + ch * 8,
                       &Bs[(size_t)(i * 256 + wave * 64) * 8]);
        }
    };

    const int nk = kspan >> 6;
    issue_loads(kstart);

    for (int it = 0; it < nk; ++it) {
        __syncthreads();   // (a) vmcnt(0) drain; flight hidden under prev MFMAs

        bf16x8 af[2][4], bfr[2][NJ];
        #pragma unroll
        for (int ks = 0; ks < 2; ++ks) {
            #pragma unroll
            for (int i = 0; i < 4; ++i) {
                int row = wm * 64 + i * 16 + l15;
                int pc = (ks * 4 + quad) ^ (row & 7);
                af[ks][i] = *(const bf16x8*)&As[row * 64 + pc * 8];
            }
            #pragma unroll
            for (int j = 0; j < NJ; ++j) {
                int row = wn * (TN / 2) + j * 16 + l15;
                int pc = (ks * 4 + quad) ^ (row & 7);
                bfr[ks][j] = *(const bf16x8*)&Bs[row * 64 + pc * 8];
            }
        }

        __syncthreads();   // (b) frag reads done -> safe to overwrite buffer

        if (it + 1 < nk) issue_loads(kstart + ((it + 1) << 6));

        #pragma unroll
        for (int ks = 0; ks < 2; ++ks)
            #pragma unroll
            for (int i = 0; i < 4; ++i)
                #pragma unroll
                for (int j = 0; j < NJ; ++j)
                    acc[i][j] = __builtin_amdgcn_mfma_f32_16x16x32_bf16(af[ks][i], bfr[ks][j], acc[i][j], 0, 0, 0);
    }

    const int mbase = m0 + wm * 64, nbase = n0 + wn * (TN / 2);
    float* po = (float*)outp + (size_t)kz * ((size_t)M * N);
    #pragma unroll
    for (int i = 0; i < 4; ++i) {
        #pragma unroll
        for (int j = 0; j < NJ; ++j) {
            int col = nbase + j * 16 + l15;
            float bv = (EPI == 3) ? 0.f : bias[col];
            #pragma unroll
            for (int r = 0; r < 4; ++r) {
                int row = mbase + i * 16 + quad * 4 + r;
                size_t idx = (size_t)row * N + col;
                float v = acc[i][j][r] + bv;
                if (EPI == 0) {
                    ((bf16*)outp)[idx] = (bf16)v;
                } else if (EPI == 1) {
                    ((float*)outp)[idx] = v + res[idx];
                } else if (EPI == 2) {
                    ((float*)outp)[idx] = res[idx] + gelu_f(v);
                } else {
                    po[idx] = v;
                }
            }
        }
    }
}

// ---------------------------------------------------------------------------
// transpose V part of QKV into VT[(bh*64+d)*1024 + s]  (B-operand layout for PV)
// ---------------------------------------------------------------------------
__global__ __launch_bounds__(256) void transpose_v(const bf16* __restrict__ qkv,
                                                   bf16* __restrict__ vt)
{
    __shared__ bf16 tile[64 * 65];
    const int t = threadIdx.x;
    const int bh = blockIdx.y, bb = bh >> 4, h = bh & 15;
    const int s0 = blockIdx.x * 64;

    #pragma unroll
    for (int i = 0; i < 2; ++i) {
        int l = t + i * 256;
        int sl = l >> 3, c = (l & 7) * 8;
        bf16x8 v = *(const bf16x8*)(qkv + (size_t)(bb * 1024 + s0 + sl) * 3072 + 2048 + h * 64 + c);
        #pragma unroll
        for (int j = 0; j < 8; ++j) tile[sl * 65 + c + j] = v[j];
    }
    __syncthreads();
    #pragma unroll
    for (int i = 0; i < 2; ++i) {
        int l = t + i * 256;
        int dl = l >> 3, sc = (l & 7) * 8;
        bf16x8 v;
        #pragma unroll
        for (int j = 0; j < 8; ++j) v[j] = tile[(sc + j) * 65 + dl];
        *(bf16x8*)(vt + (size_t)(bh * 64 + dl) * 1024 + s0 + sc) = v;
    }
}

// ---------------------------------------------------------------------------
// flash attention v5: 128 q-rows per block (512 thr / 8 waves) AND 128 keys
// per staged tile -> barrier/drain count halves vs v4 (8 tiles per block).
// The tile is computed as two 64-key sub-halves whose math is bit-identical
// to v4: swapped QK^T (S^T = mfma(K,Q)) so each lane owns one q-row of P in
// registers; K staged with the bit-permuted row map g64 applied within each
// half (LDS row sub*64+rw holds global key kt+sub*64+g64(rw)); V chunks of
// sub-half live in chunk group sub*8 (XOR swizzle stays in-group since
// (sub*8+x)^y = sub*8+(x^y), x,y<8).  Zero-shuffle P->PV hand-off.  K/V LDS
// double-buffered; per-tile ledger identical to v4: barrier drains the stage
// issued one full compute phase earlier; stage targets the buffer all waves
// finished reading before that same barrier.
// ---------------------------------------------------------------------------
__global__ __launch_bounds__(512, 2) void flash_attn(
    const bf16* __restrict__ QKV, const bf16* __restrict__ VT,
    const int* __restrict__ mask, bf16* __restrict__ outp)
{
    __shared__ __align__(16) bf16 Ks[2][128 * 64];
    __shared__ __align__(16) bf16 VTs[2][64 * 128];

    const int t = threadIdx.x;
    const int lane = t & 63, wave = t >> 6;
    const int l15 = lane & 15, quad = lane >> 4;
    const int bh = blockIdx.x, bb = bh >> 4, h = bh & 15;
    const int q0 = blockIdx.y * 128;

    // ---- stage Q (128x64, swizzled) into Ks[0] (16 KB, dead until tile 0) ----
    bf16* Qs = &Ks[0][0];
    #pragma unroll
    for (int i = 0; i < 2; ++i) {
        int l = t + i * 512;
        int row = l >> 3, c = (l & 7) ^ (row & 7);
        load_lds16(QKV + (size_t)(bb * 1024 + q0 + row) * 3072 + h * 64 + c * 8,
                   &Qs[(size_t)(i * 512 + wave * 64) * 8]);
    }
    __syncthreads();                       // Q resident (vmcnt drain)

    bf16x8 aq[2];                          // Q B-frags: row q = wave*16+l15
    #pragma unroll
    for (int ks = 0; ks < 2; ++ks) {
        int row = wave * 16 + l15;
        int pc = (ks * 4 + quad) ^ (row & 7);
        aq[ks] = *(const bf16x8*)&Qs[row * 64 + pc * 8];
    }
    __syncthreads();                       // all Q reads done -> Ks reusable

    // stage one 128-key tile: K 128x64 (8 chunks/row), VT 64x128 (16 chunks/row)
    auto stage_kv = [&](int buf, int kt) {
        #pragma unroll
        for (int i = 0; i < 2; ++i) {
            int l = t + i * 512;
            int krow = l >> 3, kc = (l & 7) ^ (krow & 7);
            // 7-bit row permute: bit6,bit5 identity + g64 on low bits
            int gr = (krow & 96) | ((krow & 12) << 1) | ((krow & 16) >> 2) | (krow & 3);
            load_lds16(QKV + (size_t)(bb * 1024 + kt + gr) * 3072 + 1024 + h * 64 + kc * 8,
                       &Ks[buf][(size_t)(i * 512 + wave * 64) * 8]);
            int vrow = l >> 4, vc = (l & 15) ^ (vrow & 7);
            load_lds16(VT + (size_t)(bh * 64 + vrow) * 1024 + kt + vc * 8,
                       &VTs[buf][(size_t)(i * 512 + wave * 64) * 8]);
        }
    };
    stage_kv(0, 0);

    floatx4 acc_o[4] = {};                 // O[q=quad*4+r][d=nt2*16+l15]
    float m_st = -1e30f, l_st = 0.f;       // stats for q = l15 (per lane)
    const float SC2 = 0.18033688011112042f;   // 0.125 * log2(e)
    const float MB  = -1.442695e9f;           // -1e9 * log2(e)
    const int* mrow = mask + bb * 1024;

    for (int kt = 0; kt < 1024; kt += 128) {
        const int buf = (kt >> 7) & 1;
        __syncthreads();   // drains buf's loads (issued one compute phase ago)
        if (kt + 128 < 1024) stage_kv(buf ^ 1, kt + 128);

        int mv[2];
        mv[0] = mrow[kt + lane];
        mv[1] = mrow[kt + 64 + lane];

        #pragma unroll
        for (int sub = 0; sub < 2; ++sub) {
            const bf16* Kb = &Ks[buf][sub * 64 * 64];

            // K A-frags (LDS rows nt*16+l15 within half, content g64-permuted)
            bf16x8 kf[2][4];
            #pragma unroll
            for (int ks = 0; ks < 2; ++ks)
                #pragma unroll
                for (int nt = 0; nt < 4; ++nt) {
                    int row = nt * 16 + l15;
                    int pc = (ks * 4 + quad) ^ (row & 7);
                    kf[ks][nt] = *(const bf16x8*)&Kb[row * 64 + pc * 8];
                }

            // S^T: st[k = g64(nt*16+quad*4+r)][q = l15]
            floatx4 s[4] = {};
            #pragma unroll
            for (int ks = 0; ks < 2; ++ks)
                #pragma unroll
                for (int nt = 0; nt < 4; ++nt)
                    s[nt] = __builtin_amdgcn_mfma_f32_16x16x32_bf16(kf[ks][nt], aq[ks], s[nt], 0, 0, 0);

            // V B-frags (chunk group sub*8): ds_read latency hides under softmax
            bf16x8 vf[2][4];
            #pragma unroll
            for (int ks = 0; ks < 2; ++ks)
                #pragma unroll
                for (int nt2 = 0; nt2 < 4; ++nt2) {
                    int row = nt2 * 16 + l15;
                    int pc = (sub * 8 + ks * 4 + quad) ^ (row & 7);
                    vf[ks][nt2] = *(const bf16x8*)&VTs[buf][row * 128 + pc * 8];
                }

            // scale (+ mask bias only on slow path)
            float sv[4][4];
            if (__all(mv[sub] != 0)) {
                #pragma unroll
                for (int nt = 0; nt < 4; ++nt)
                    #pragma unroll
                    for (int r = 0; r < 4; ++r)
                        sv[nt][r] = s[nt][r] * SC2;
            } else {
                #pragma unroll
                for (int nt = 0; nt < 4; ++nt)
                    #pragma unroll
                    for (int r = 0; r < 4; ++r) {
                        int kg = ((nt >> 1) << 5) | (quad << 3) | ((nt & 1) << 2) | r;
                        int mk = __shfl(mv[sub], kg, 64);
                        sv[nt][r] = fmaf(s[nt][r], SC2, mk ? 0.f : MB);
                    }
            }

            // row max: local over lane's 16 k, then cross-quad butterfly
            float mx = sv[0][0];
            #pragma unroll
            for (int nt = 0; nt < 4; ++nt)
                #pragma unroll
                for (int r = 0; r < 4; ++r)
                    mx = fmaxf(mx, sv[nt][r]);
            mx = fmaxf(mx, __shfl_xor(mx, 16, 64));
            mx = fmaxf(mx, __shfl_xor(mx, 32, 64));

            // defer-max rescale (rare): alpha at q=l15, O rows at quad*4+r
            if (__any(mx > m_st + 12.0f)) {
                float mnew = fmaxf(m_st, mx);
                float al = __builtin_amdgcn_exp2f(m_st - mnew);
                m_st = mnew;
                l_st *= al;
                #pragma unroll
                for (int r = 0; r < 4; ++r) {
                    float alr = __shfl(al, quad * 4 + r, 64);
                    #pragma unroll
                    for (int nt2 = 0; nt2 < 4; ++nt2) acc_o[nt2][r] *= alr;
                }
            }

            // p = exp2(sv - m); build PV A-frags directly in registers
            bf16x8 pa[2];
            float rs = 0.f;
            #pragma unroll
            for (int nt = 0; nt < 4; ++nt)
                #pragma unroll
                for (int r = 0; r < 4; ++r) {
                    float p = __builtin_amdgcn_exp2f(sv[nt][r] - m_st);
                    rs += p;
                    pa[nt >> 1][(nt & 1) * 4 + r] = (bf16)p;
                }
            l_st += rs;

            // O += P * V
            #pragma unroll
            for (int ks = 0; ks < 2; ++ks)
                #pragma unroll
                for (int nt2 = 0; nt2 < 4; ++nt2)
                    acc_o[nt2] = __builtin_amdgcn_mfma_f32_16x16x32_bf16(pa[ks], vf[ks][nt2], acc_o[nt2], 0, 0, 0);
        }
    }

    // epilogue: reduce l across quads, redistribute to O-row owners, divide
    float lt = l_st;
    lt += __shfl_xor(lt, 16, 64);
    lt += __shfl_xor(lt, 32, 64);
    #pragma unroll
    for (int r = 0; r < 4; ++r) {
        float lr = __shfl(lt, quad * 4 + r, 64);
        float linv = __builtin_amdgcn_rcpf(lr);
        int qrow = q0 + wave * 16 + quad * 4 + r;
        #pragma unroll
        for (int nt2 = 0; nt2 < 4; ++nt2) {
            int dd = nt2 * 16 + l15;
            outp[(size_t)(bb * 1024 + qrow) * 1024 + h * 64 + dd] = (bf16)(acc_o[nt2][r] * linv);
        }
    }
}

// ---------------------------------------------------------------------------
// Fused LayerNorm (torch clone: unbiased var, /(std+eps)) over split-K
// partial sums.  MODE 0: v = res + p0 + p1 + bias           (post-O-proj)
//                 MODE 1: v = res + gelu(p0 + p1 + bias)    (post-FFN2)
// ---------------------------------------------------------------------------
template <int MODE>
__global__ __launch_bounds__(256) void ln_fuse(
    const float* __restrict__ part, const float* __restrict__ res,
    const float* __restrict__ bias, const float* __restrict__ g,
    const float* __restrict__ b, bf16* __restrict__ obf, float* __restrict__ of)
{
    const int row = blockIdx.x;
    const size_t base = (size_t)row * 1024;
    float4 p0 = ((const float4*)(part + base))[threadIdx.x];
    float4 p1 = ((const float4*)(part + 4194304 + base))[threadIdx.x];  // +NT*1024
    float4 rv = ((const float4*)(res + base))[threadIdx.x];
    float4 bi = ((const float4*)bias)[threadIdx.x];
    float4 v;
    if (MODE == 0) {
        v.x = rv.x + p0.x + p1.x + bi.x;
        v.y = rv.y + p0.y + p1.y + bi.y;
        v.z = rv.z + p0.z + p1.z + bi.z;
        v.w = rv.w + p0.w + p1.w + bi.w;
    } else {
        v.x = rv.x + gelu_f(p0.x + p1.x + bi.x);
        v.y = rv.y + gelu_f(p0.y + p1.y + bi.y);
        v.z = rv.z + gelu_f(p0.z + p1.z + bi.z);
        v.w = rv.w + gelu_f(p0.w + p1.w + bi.w);
    }

    float s = v.x + v.y + v.z + v.w;
    float s2 = v.x * v.x + v.y * v.y + v.z * v.z + v.w * v.w;
    #pragma unroll
    for (int o = 32; o >= 1; o >>= 1) {
        s += __shfl_down(s, o, 64);
        s2 += __shfl_down(s2, o, 64);
    }
    __shared__ float red[8];
    if ((threadIdx.x & 63) == 0) {
        red[threadIdx.x >> 6] = s;
        red[4 + (threadIdx.x >> 6)] = s2;
    }
    __syncthreads();
    s = red[0] + red[1] + red[2] + red[3];
    s2 = red[4] + red[5] + red[6] + red[7];
    float mean = s * (1.f / 1024.f);
    float var = fmaxf(0.f, s2 - 1024.f * mean * mean) * (1.f / 1023.f);
    float inv = 1.f / (sqrtf(var) + 1e-6f);
    float4 gg = ((const float4*)g)[threadIdx.x];
    float4 bb = ((const float4*)b)[threadIdx.x];
    float4 o;
    o.x = gg.x * (v.x - mean) * inv + bb.x;
    o.y = gg.y * (v.y - mean) * inv + bb.y;
    o.z = gg.z * (v.z - mean) * inv + bb.z;
    o.w = gg.w * (v.w - mean) * inv + bb.w;
    if (of) ((float4*)(of + base))[threadIdx.x] = o;
    if (obf) {
        ushort4 u;
        u.x = f2bf(o.x); u.y = f2bf(o.y); u.z = f2bf(o.z); u.w = f2bf(o.w);
        ((ushort4*)(obf + base))[threadIdx.x] = u;
    }
}

// ---------------------------------------------------------------------------
// workspace layout (bytes)
// ---------------------------------------------------------------------------
constexpr size_t OFF_XBF   = 0;                         // 8388608  (reused: attn out)
constexpr size_t OFF_WQKV  = OFF_XBF + 8388608;         // 6291456
constexpr size_t OFF_BQKV  = OFF_WQKV + 6291456;        // 16384
constexpr size_t OFF_WO    = OFF_BQKV + 16384;          // 2097152
constexpr size_t OFF_W1    = OFF_WO + 2097152;          // 8388608
constexpr size_t OFF_W2    = OFF_W1 + 8388608;          // 8388608
constexpr size_t OFF_QKV   = OFF_W2 + 8388608;          // 25165824
constexpr size_t OFF_VT    = OFF_QKV + 25165824;        // 8388608
// PART aliases QKV+VT (32 MB contiguous): both dead when partials are live.
constexpr size_t OFF_PART  = OFF_QKV;
constexpr size_t OFF_X1BF  = OFF_VT + 8388608;          // 8388608
constexpr size_t OFF_X1F   = OFF_X1BF + 8388608;        // 16777216
constexpr size_t OFF_H1    = OFF_X1F + 16777216;        // 33554432
// total: 125845504 bytes (~120 MB)

extern "C" void kernel_launch(void* const* d_in, const int* in_sizes, int n_in,
                              void* d_out, int out_size, void* d_ws, size_t ws_size,
                              hipStream_t stream)
{
    const float* query = (const float*)d_in[0];
    const int*   maskp = (const int*)d_in[3];
    const float* Wq = (const float*)d_in[4];
    const float* bq = (const float*)d_in[5];
    const float* Wk = (const float*)d_in[6];
    const float* bk = (const float*)d_in[7];
    const float* Wv = (const float*)d_in[8];
    const float* bv = (const float*)d_in[9];
    const float* Wo = (const float*)d_in[10];
    const float* bo = (const float*)d_in[11];
    const float* W1 = (const float*)d_in[12];
    const float* b1 = (const float*)d_in[13];
    const float* W2 = (const float*)d_in[14];
    const float* b2 = (const float*)d_in[15];
    const float* g1 = (const float*)d_in[16];
    const float* be1 = (const float*)d_in[17];
    const float* g2 = (const float*)d_in[18];
    const float* be2 = (const float*)d_in[19];

    char* ws = (char*)d_ws;
    bf16*  xbf   = (bf16*)(ws + OFF_XBF);
    bf16*  wqkv  = (bf16*)(ws + OFF_WQKV);
    float* bqkv  = (float*)(ws + OFF_BQKV);
    bf16*  wob   = (bf16*)(ws + OFF_WO);
    bf16*  w1b   = (bf16*)(ws + OFF_W1);
    bf16*  w2b   = (bf16*)(ws + OFF_W2);
    bf16*  qkv   = (bf16*)(ws + OFF_QKV);
    bf16*  vt    = (bf16*)(ws + OFF_VT);
    float* part  = (float*)(ws + OFF_PART); // alias: qkv+vt dead when used
    bf16*  x1bf  = (bf16*)(ws + OFF_X1BF);
    float* x1f   = (float*)(ws + OFF_X1F);
    bf16*  h1    = (bf16*)(ws + OFF_H1);
    bf16*  attn  = (bf16*)(ws + OFF_XBF);   // alias: xbf dead after QKV GEMM
    float* outf  = (float*)d_out;

    cast_kernel<<<16384, 256, 0, stream>>>(query, Wq, Wk, Wv, Wo, W1, W2, bq, bk, bv,
                                           xbf, wqkv, wob, w1b, w2b, bqkv);
    gemm_bt<0, 128><<<dim3(32, 24), 256, 0, stream>>>(xbf, wqkv, bqkv, nullptr, qkv, NT, 3072, 1024);
    transpose_v<<<dim3(16, 64), 256, 0, stream>>>(qkv, vt);
    flash_attn<<<dim3(64, 8), 512, 0, stream>>>(qkv, vt, maskp, attn);
    // O-proj: split-K=2, raw f32 partials; epilogue folded into ln_fuse<0>
    gemm_bt<3, 128, 2><<<dim3(32, 8, 2), 256, 0, stream>>>(attn, wob, nullptr, nullptr, part, NT, 1024, 1024);
    ln_fuse<0><<<4096, 256, 0, stream>>>(part, query, bo, g1, be1, x1bf, x1f);
    gemm_bt<0, 128><<<dim3(32, 32), 256, 0, stream>>>(x1bf, w1b, b1, nullptr, h1, NT, 4096, 1024);
    // FFN2: split-K=2, raw f32 partials; gelu+res folded into ln_fuse<1>
    gemm_bt<3, 128, 2><<<dim3(32, 8, 2), 256, 0, stream>>>(h1, w2b, nullptr, nullptr, part, NT, 1024, 4096);
    ln_fuse<1><<<4096, 256, 0, stream>>>(part, x1f, b2, g2, be2, nullptr, outf);
}

// Round 10
// 318.618 us; speedup vs baseline: 1.0939x; 1.0939x over previous
//
#include <hip/hip_runtime.h>
#include <hip/hip_bf16.h>
#include <math.h>

typedef __bf16 bf16;
typedef __bf16 bf16x8 __attribute__((ext_vector_type(8)));
typedef float floatx4 __attribute__((ext_vector_type(4)));

#define NT 4096        // B*S tokens
#define DMODEL 1024
#define NHEAD 16
#define DHEAD 64
#define FFDIM 4096

__device__ __forceinline__ void load_lds16(const void* g, void* l) {
    __builtin_amdgcn_global_load_lds(
        (const __attribute__((address_space(1))) void*)g,
        (__attribute__((address_space(3))) void*)l,
        16, 0, 0);
}

__device__ __forceinline__ unsigned short f2bf(float f) {
    bf16 h = (bf16)f;
    return __builtin_bit_cast(unsigned short, h);
}

__device__ __forceinline__ float gelu_f(float v) {
    return 0.5f * v * (1.0f + tanhf(0.7978845608028654f * (v + 0.044715f * v * v * v)));
}

// ---------------------------------------------------------------------------
// cast fp32 -> bf16 for query + all weights; build concat qkv bias
// ---------------------------------------------------------------------------
__global__ __launch_bounds__(256) void cast_kernel(
    const float* __restrict__ q, const float* __restrict__ wq, const float* __restrict__ wk,
    const float* __restrict__ wv, const float* __restrict__ wo, const float* __restrict__ w1,
    const float* __restrict__ w2, const float* __restrict__ bq, const float* __restrict__ bk,
    const float* __restrict__ bv, bf16* __restrict__ xbf, bf16* __restrict__ wqkv,
    bf16* __restrict__ wob, bf16* __restrict__ w1b, bf16* __restrict__ w2b,
    float* __restrict__ bqkv)
{
    int gid = blockIdx.x * 256 + threadIdx.x;
    if (gid < 3072)
        bqkv[gid] = gid < 1024 ? bq[gid] : (gid < 2048 ? bk[gid - 1024] : bv[gid - 2048]);

    const float4* src;
    ushort4* dst;
    int off = gid;
    if (off < 1048576)                  { src = (const float4*)q;  dst = (ushort4*)xbf; }
    else if ((off -= 1048576) < 262144) { src = (const float4*)wq; dst = (ushort4*)wqkv; }
    else if ((off -= 262144) < 262144)  { src = (const float4*)wk; dst = (ushort4*)wqkv + 262144; }
    else if ((off -= 262144) < 262144)  { src = (const float4*)wv; dst = (ushort4*)wqkv + 524288; }
    else if ((off -= 262144) < 262144)  { src = (const float4*)wo; dst = (ushort4*)wob; }
    else if ((off -= 262144) < 1048576) { src = (const float4*)w1; dst = (ushort4*)w1b; }
    else { off -= 1048576;                src = (const float4*)w2; dst = (ushort4*)w2b; }

    float4 v = src[off];
    ushort4 u;
    u.x = f2bf(v.x); u.y = f2bf(v.y); u.z = f2bf(v.z); u.w = f2bf(v.w);
    dst[off] = u;
}

// ---------------------------------------------------------------------------
// GEMM: C[M,N] = A[M,K] * W[N,K]^T + bias.  Tile 128 x TN, BK=64,
// SINGLE-buffered LDS, optional split-K (blockIdx.z -> f32 partial plane).
// Per iter: sync -> ds_read ALL frags -> sync -> issue next tile's
// global_load_lds -> MFMAs (hide load flight under MFMA).
// Staging source addresses XOR-swizzled (ch ^= row&7).
// EPI=0: bf16 = acc+bias | EPI=1: f32 = acc+bias+res | EPI=2: f32 =
// res+gelu(acc+bias) | EPI=3: f32 raw partial plane.
// ---------------------------------------------------------------------------
template <int EPI, int TN, int SPLITK = 1>
__global__ __launch_bounds__(256) void gemm_bt(
    const bf16* __restrict__ A, const bf16* __restrict__ Wt,
    const float* __restrict__ bias, const float* __restrict__ res,
    void* __restrict__ outp, int M, int N, int K)
{
    constexpr int NJ = TN / 32;          // n-frags per wave (4 or 2)
    __shared__ __align__(16) bf16 As[128 * 64];
    __shared__ __align__(16) bf16 Bs[TN * 64];

    const int t = threadIdx.x;
    const int lane = t & 63, wave = t >> 6;
    const int l15 = lane & 15, quad = lane >> 4;
    const int wm = wave & 1, wn = wave >> 1;
    const int m0 = blockIdx.x * 128, n0 = blockIdx.y * TN;
    const int kz = (SPLITK > 1) ? blockIdx.z : 0;
    const int kspan = K / SPLITK;
    const int kstart = kz * kspan;

    floatx4 acc[4][NJ] = {};

    auto issue_loads = [&](int k0) {
        #pragma unroll
        for (int i = 0; i < 4; ++i) {
            int l = t + i * 256;
            int row = l >> 3, ch = (l & 7) ^ (row & 7);
            load_lds16(A + (size_t)(m0 + row) * K + k0 + ch * 8,
                       &As[(size_t)(i * 256 + wave * 64) * 8]);
        }
        #pragma unroll
        for (int i = 0; i < TN / 32; ++i) {
            int l = t + i * 256;
            int row = l >> 3, ch = (l & 7) ^ (row & 7);
            load_lds16(Wt + (size_t)(n0 + row) * K + k0 + ch * 8,
                       &Bs[(size_t)(i * 256 + wave * 64) * 8]);
        }
    };

    const int nk = kspan >> 6;
    issue_loads(kstart);

    for (int it = 0; it < nk; ++it) {
        __syncthreads();   // (a) vmcnt(0) drain; flight hidden under prev MFMAs

        bf16x8 af[2][4], bfr[2][NJ];
        #pragma unroll
        for (int ks = 0; ks < 2; ++ks) {
            #pragma unroll
            for (int i = 0; i < 4; ++i) {
                int row = wm * 64 + i * 16 + l15;
                int pc = (ks * 4 + quad) ^ (row & 7);
                af[ks][i] = *(const bf16x8*)&As[row * 64 + pc * 8];
            }
            #pragma unroll
            for (int j = 0; j < NJ; ++j) {
                int row = wn * (TN / 2) + j * 16 + l15;
                int pc = (ks * 4 + quad) ^ (row & 7);
                bfr[ks][j] = *(const bf16x8*)&Bs[row * 64 + pc * 8];
            }
        }

        __syncthreads();   // (b) frag reads done -> safe to overwrite buffer

        if (it + 1 < nk) issue_loads(kstart + ((it + 1) << 6));

        #pragma unroll
        for (int ks = 0; ks < 2; ++ks)
            #pragma unroll
            for (int i = 0; i < 4; ++i)
                #pragma unroll
                for (int j = 0; j < NJ; ++j)
                    acc[i][j] = __builtin_amdgcn_mfma_f32_16x16x32_bf16(af[ks][i], bfr[ks][j], acc[i][j], 0, 0, 0);
    }

    const int mbase = m0 + wm * 64, nbase = n0 + wn * (TN / 2);
    float* po = (float*)outp + (size_t)kz * ((size_t)M * N);
    #pragma unroll
    for (int i = 0; i < 4; ++i) {
        #pragma unroll
        for (int j = 0; j < NJ; ++j) {
            int col = nbase + j * 16 + l15;
            float bv = (EPI == 3) ? 0.f : bias[col];
            #pragma unroll
            for (int r = 0; r < 4; ++r) {
                int row = mbase + i * 16 + quad * 4 + r;
                size_t idx = (size_t)row * N + col;
                float v = acc[i][j][r] + bv;
                if (EPI == 0) {
                    ((bf16*)outp)[idx] = (bf16)v;
                } else if (EPI == 1) {
                    ((float*)outp)[idx] = v + res[idx];
                } else if (EPI == 2) {
                    ((float*)outp)[idx] = res[idx] + gelu_f(v);
                } else {
                    po[idx] = v;
                }
            }
        }
    }
}

// ---------------------------------------------------------------------------
// transpose V part of QKV into VT[(bh*64+d)*1024 + s]  (B-operand layout for PV)
// ---------------------------------------------------------------------------
__global__ __launch_bounds__(256) void transpose_v(const bf16* __restrict__ qkv,
                                                   bf16* __restrict__ vt)
{
    __shared__ bf16 tile[64 * 65];
    const int t = threadIdx.x;
    const int bh = blockIdx.y, bb = bh >> 4, h = bh & 15;
    const int s0 = blockIdx.x * 64;

    #pragma unroll
    for (int i = 0; i < 2; ++i) {
        int l = t + i * 256;
        int sl = l >> 3, c = (l & 7) * 8;
        bf16x8 v = *(const bf16x8*)(qkv + (size_t)(bb * 1024 + s0 + sl) * 3072 + 2048 + h * 64 + c);
        #pragma unroll
        for (int j = 0; j < 8; ++j) tile[sl * 65 + c + j] = v[j];
    }
    __syncthreads();
    #pragma unroll
    for (int i = 0; i < 2; ++i) {
        int l = t + i * 256;
        int dl = l >> 3, sc = (l & 7) * 8;
        bf16x8 v;
        #pragma unroll
        for (int j = 0; j < 8; ++j) v[j] = tile[(sc + j) * 65 + dl];
        *(bf16x8*)(vt + (size_t)(bh * 64 + dl) * 1024 + s0 + sc) = v;
    }
}

// ---------------------------------------------------------------------------
// flash attention v4: 128 q-rows per block, 512 threads / 8 waves sharing one
// K/V staging (wave w owns q-rows [16w,16w+16)).  Swapped QK^T
// (S^T = mfma(K,Q)) so each lane owns one q-row of P in registers; K staged
// with bit-permuted row map g(rw) = rw&32 | (rw&12)<<1 | (rw&16)>>2 | rw&3
// so the 16 P values a lane holds are exactly the two PV A-fragments
// (zero-shuffle hand-off).  K/V LDS double-buffered, one barrier per tile.
// ---------------------------------------------------------------------------
__global__ __launch_bounds__(512, 4) void flash_attn(
    const bf16* __restrict__ QKV, const bf16* __restrict__ VT,
    const int* __restrict__ mask, bf16* __restrict__ outp)
{
    __shared__ __align__(16) bf16 Ks[2][64 * 64];
    __shared__ __align__(16) bf16 VTs[2][64 * 64];

    const int t = threadIdx.x;
    const int lane = t & 63, wave = t >> 6;
    const int l15 = lane & 15, quad = lane >> 4;
    const int bh = blockIdx.x, bb = bh >> 4, h = bh & 15;
    const int q0 = blockIdx.y * 128;

    // ---- stage Q (128x64, swizzled) into Ks[0..1] (contiguous 16 KB) ----
    bf16* Qs = &Ks[0][0];
    #pragma unroll
    for (int i = 0; i < 2; ++i) {
        int l = t + i * 512;
        int row = l >> 3, c = (l & 7) ^ (row & 7);
        load_lds16(QKV + (size_t)(bb * 1024 + q0 + row) * 3072 + h * 64 + c * 8,
                   &Qs[(size_t)(i * 512 + wave * 64) * 8]);
    }
    __syncthreads();                       // Q resident (vmcnt drain)

    bf16x8 aq[2];                          // Q B-frags: row q = wave*16+l15
    #pragma unroll
    for (int ks = 0; ks < 2; ++ks) {
        int row = wave * 16 + l15;
        int pc = (ks * 4 + quad) ^ (row & 7);
        aq[ks] = *(const bf16x8*)&Qs[row * 64 + pc * 8];
    }
    __syncthreads();                       // all Q reads done -> Ks reusable

    // 512 threads stage one 64x64 tile each for K and VT (1 slot/thread)
    auto stage_kv = [&](int buf, int kt) {
        int row = t >> 3, c = (t & 7) ^ (row & 7);
        int gr = (row & 32) | ((row & 12) << 1) | ((row & 16) >> 2) | (row & 3);
        load_lds16(QKV + (size_t)(bb * 1024 + kt + gr) * 3072 + 1024 + h * 64 + c * 8,
                   &Ks[buf][(size_t)(wave * 64) * 8]);
        load_lds16(VT + (size_t)(bh * 64 + row) * 1024 + kt + c * 8,
                   &VTs[buf][(size_t)(wave * 64) * 8]);
    };
    stage_kv(0, 0);

    floatx4 acc_o[4] = {};                 // O[q=quad*4+r][d=nt2*16+l15]
    float m_st = -1e30f, l_st = 0.f;       // stats for q = l15 (per lane)
    const float SC2 = 0.18033688011112042f;   // 0.125 * log2(e)
    const float MB  = -1.442695e9f;           // -1e9 * log2(e)
    const int* mrow = mask + bb * 1024;

    for (int kt = 0; kt < 1024; kt += 64) {
        const int buf = (kt >> 6) & 1;
        __syncthreads();   // drains buf's loads (issued one compute phase ago)
        if (kt + 64 < 1024) stage_kv(buf ^ 1, kt + 64);

        int mv = mrow[kt + lane];          // coalesced, whole tile's mask

        // K A-frags (LDS rows nt*16+l15, content row-permuted by g)
        bf16x8 kf[2][4];
        #pragma unroll
        for (int ks = 0; ks < 2; ++ks)
            #pragma unroll
            for (int nt = 0; nt < 4; ++nt) {
                int row = nt * 16 + l15;
                int pc = (ks * 4 + quad) ^ (row & 7);
                kf[ks][nt] = *(const bf16x8*)&Ks[buf][row * 64 + pc * 8];
            }

        // S^T: st[k = g(nt*16+quad*4+r)][q = l15]
        floatx4 s[4] = {};
        #pragma unroll
        for (int ks = 0; ks < 2; ++ks)
            #pragma unroll
            for (int nt = 0; nt < 4; ++nt)
                s[nt] = __builtin_amdgcn_mfma_f32_16x16x32_bf16(kf[ks][nt], aq[ks], s[nt], 0, 0, 0);

        // V B-frags issued here: ds_read latency hides under softmax VALU
        bf16x8 vf[2][4];
        #pragma unroll
        for (int ks = 0; ks < 2; ++ks)
            #pragma unroll
            for (int nt2 = 0; nt2 < 4; ++nt2) {
                int row = nt2 * 16 + l15;
                int pc = (ks * 4 + quad) ^ (row & 7);
                vf[ks][nt2] = *(const bf16x8*)&VTs[buf][row * 64 + pc * 8];
            }

        // scale (+ mask bias only on slow path; lane's k = g(nt*16+quad*4+r))
        float sv[4][4];
        if (__all(mv != 0)) {
            #pragma unroll
            for (int nt = 0; nt < 4; ++nt)
                #pragma unroll
                for (int r = 0; r < 4; ++r)
                    sv[nt][r] = s[nt][r] * SC2;
        } else {
            #pragma unroll
            for (int nt = 0; nt < 4; ++nt)
                #pragma unroll
                for (int r = 0; r < 4; ++r) {
                    int kg = ((nt >> 1) << 5) | (quad << 3) | ((nt & 1) << 2) | r;
                    int mk = __shfl(mv, kg, 64);
                    sv[nt][r] = fmaf(s[nt][r], SC2, mk ? 0.f : MB);
                }
        }

        // row max: local over lane's 16 k, then cross-quad butterfly
        float mx = sv[0][0];
        #pragma unroll
        for (int nt = 0; nt < 4; ++nt)
            #pragma unroll
            for (int r = 0; r < 4; ++r)
                mx = fmaxf(mx, sv[nt][r]);
        mx = fmaxf(mx, __shfl_xor(mx, 16, 64));
        mx = fmaxf(mx, __shfl_xor(mx, 32, 64));

        // defer-max rescale (rare): alpha lives at q=l15, O rows at quad*4+r
        if (__any(mx > m_st + 12.0f)) {
            float mnew = fmaxf(m_st, mx);
            float al = __builtin_amdgcn_exp2f(m_st - mnew);
            m_st = mnew;
            l_st *= al;
            #pragma unroll
            for (int r = 0; r < 4; ++r) {
                float alr = __shfl(al, quad * 4 + r, 64);
                #pragma unroll
                for (int nt2 = 0; nt2 < 4; ++nt2) acc_o[nt2][r] *= alr;
            }
        }

        // p = exp2(sv - m); build PV A-frags directly in registers
        bf16x8 pa[2];
        float rs = 0.f;
        #pragma unroll
        for (int nt = 0; nt < 4; ++nt)
            #pragma unroll
            for (int r = 0; r < 4; ++r) {
                float p = __builtin_amdgcn_exp2f(sv[nt][r] - m_st);
                rs += p;
                pa[nt >> 1][(nt & 1) * 4 + r] = (bf16)p;
            }
        l_st += rs;

        // O += P * V
        #pragma unroll
        for (int ks = 0; ks < 2; ++ks)
            #pragma unroll
            for (int nt2 = 0; nt2 < 4; ++nt2)
                acc_o[nt2] = __builtin_amdgcn_mfma_f32_16x16x32_bf16(pa[ks], vf[ks][nt2], acc_o[nt2], 0, 0, 0);
    }

    // epilogue: reduce l across quads, redistribute to O-row owners, divide
    float lt = l_st;
    lt += __shfl_xor(lt, 16, 64);
    lt += __shfl_xor(lt, 32, 64);
    #pragma unroll
    for (int r = 0; r < 4; ++r) {
        float lr = __shfl(lt, quad * 4 + r, 64);
        float linv = __builtin_amdgcn_rcpf(lr);
        int qrow = q0 + wave * 16 + quad * 4 + r;
        #pragma unroll
        for (int nt2 = 0; nt2 < 4; ++nt2) {
            int dd = nt2 * 16 + l15;
            outp[(size_t)(bb * 1024 + qrow) * 1024 + h * 64 + dd] = (bf16)(acc_o[nt2][r] * linv);
        }
    }
}

// ---------------------------------------------------------------------------
// Fused LayerNorm (torch clone: unbiased var, /(std+eps)) over split-K
// partial sums.  MODE 0: v = res + p0 + p1 + bias           (post-O-proj)
//                 MODE 1: v = res + gelu(p0 + p1 + bias)    (post-FFN2)
// ---------------------------------------------------------------------------
template <int MODE>
__global__ __launch_bounds__(256) void ln_fuse(
    const float* __restrict__ part, const float* __restrict__ res,
    const float* __restrict__ bias, const float* __restrict__ g,
    const float* __restrict__ b, bf16* __restrict__ obf, float* __restrict__ of)
{
    const int row = blockIdx.x;
    const size_t base = (size_t)row * 1024;
    float4 p0 = ((const float4*)(part + base))[threadIdx.x];
    float4 p1 = ((const float4*)(part + 4194304 + base))[threadIdx.x];  // +NT*1024
    float4 rv = ((const float4*)(res + base))[threadIdx.x];
    float4 bi = ((const float4*)bias)[threadIdx.x];
    float4 v;
    if (MODE == 0) {
        v.x = rv.x + p0.x + p1.x + bi.x;
        v.y = rv.y + p0.y + p1.y + bi.y;
        v.z = rv.z + p0.z + p1.z + bi.z;
        v.w = rv.w + p0.w + p1.w + bi.w;
    } else {
        v.x = rv.x + gelu_f(p0.x + p1.x + bi.x);
        v.y = rv.y + gelu_f(p0.y + p1.y + bi.y);
        v.z = rv.z + gelu_f(p0.z + p1.z + bi.z);
        v.w = rv.w + gelu_f(p0.w + p1.w + bi.w);
    }

    float s = v.x + v.y + v.z + v.w;
    float s2 = v.x * v.x + v.y * v.y + v.z * v.z + v.w * v.w;
    #pragma unroll
    for (int o = 32; o >= 1; o >>= 1) {
        s += __shfl_down(s, o, 64);
        s2 += __shfl_down(s2, o, 64);
    }
    __shared__ float red[8];
    if ((threadIdx.x & 63) == 0) {
        red[threadIdx.x >> 6] = s;
        red[4 + (threadIdx.x >> 6)] = s2;
    }
    __syncthreads();
    s = red[0] + red[1] + red[2] + red[3];
    s2 = red[4] + red[5] + red[6] + red[7];
    float mean = s * (1.f / 1024.f);
    float var = fmaxf(0.f, s2 - 1024.f * mean * mean) * (1.f / 1023.f);
    float inv = 1.f / (sqrtf(var) + 1e-6f);
    float4 gg = ((const float4*)g)[threadIdx.x];
    float4 bb = ((const float4*)b)[threadIdx.x];
    float4 o;
    o.x = gg.x * (v.x - mean) * inv + bb.x;
    o.y = gg.y * (v.y - mean) * inv + bb.y;
    o.z = gg.z * (v.z - mean) * inv + bb.z;
    o.w = gg.w * (v.w - mean) * inv + bb.w;
    if (of) ((float4*)(of + base))[threadIdx.x] = o;
    if (obf) {
        ushort4 u;
        u.x = f2bf(o.x); u.y = f2bf(o.y); u.z = f2bf(o.z); u.w = f2bf(o.w);
        ((ushort4*)(obf + base))[threadIdx.x] = u;
    }
}

// ---------------------------------------------------------------------------
// workspace layout (bytes)
// ---------------------------------------------------------------------------
constexpr size_t OFF_XBF   = 0;                         // 8388608  (reused: attn out)
constexpr size_t OFF_WQKV  = OFF_XBF + 8388608;         // 6291456
constexpr size_t OFF_BQKV  = OFF_WQKV + 6291456;        // 16384
constexpr size_t OFF_WO    = OFF_BQKV + 16384;          // 2097152
constexpr size_t OFF_W1    = OFF_WO + 2097152;          // 8388608
constexpr size_t OFF_W2    = OFF_W1 + 8388608;          // 8388608
constexpr size_t OFF_QKV   = OFF_W2 + 8388608;          // 25165824
constexpr size_t OFF_VT    = OFF_QKV + 25165824;        // 8388608
// PART aliases QKV+VT (32 MB contiguous): both dead when partials are live.
constexpr size_t OFF_PART  = OFF_QKV;
constexpr size_t OFF_X1BF  = OFF_VT + 8388608;          // 8388608
constexpr size_t OFF_X1F   = OFF_X1BF + 8388608;        // 16777216
constexpr size_t OFF_H1    = OFF_X1F + 16777216;        // 33554432
// total: 125845504 bytes (~120 MB)

extern "C" void kernel_launch(void* const* d_in, const int* in_sizes, int n_in,
                              void* d_out, int out_size, void* d_ws, size_t ws_size,
                              hipStream_t stream)
{
    const float* query = (const float*)d_in[0];
    const int*   maskp = (const int*)d_in[3];
    const float* Wq = (const float*)d_in[4];
    const float* bq = (const float*)d_in[5];
    const float* Wk = (const float*)d_in[6];
    const float* bk = (const float*)d_in[7];
    const float* Wv = (const float*)d_in[8];
    const float* bv = (const float*)d_in[9];
    const float* Wo = (const float*)d_in[10];
    const float* bo = (const float*)d_in[11];
    const float* W1 = (const float*)d_in[12];
    const float* b1 = (const float*)d_in[13];
    const float* W2 = (const float*)d_in[14];
    const float* b2 = (const float*)d_in[15];
    const float* g1 = (const float*)d_in[16];
    const float* be1 = (const float*)d_in[17];
    const float* g2 = (const float*)d_in[18];
    const float* be2 = (const float*)d_in[19];

    char* ws = (char*)d_ws;
    bf16*  xbf   = (bf16*)(ws + OFF_XBF);
    bf16*  wqkv  = (bf16*)(ws + OFF_WQKV);
    float* bqkv  = (float*)(ws + OFF_BQKV);
    bf16*  wob   = (bf16*)(ws + OFF_WO);
    bf16*  w1b   = (bf16*)(ws + OFF_W1);
    bf16*  w2b   = (bf16*)(ws + OFF_W2);
    bf16*  qkv   = (bf16*)(ws + OFF_QKV);
    bf16*  vt    = (bf16*)(ws + OFF_VT);
    float* part  = (float*)(ws + OFF_PART); // alias: qkv+vt dead when used
    bf16*  x1bf  = (bf16*)(ws + OFF_X1BF);
    float* x1f   = (float*)(ws + OFF_X1F);
    bf16*  h1    = (bf16*)(ws + OFF_H1);
    bf16*  attn  = (bf16*)(ws + OFF_XBF);   // alias: xbf dead after QKV GEMM
    float* outf  = (float*)d_out;

    cast_kernel<<<16384, 256, 0, stream>>>(query, Wq, Wk, Wv, Wo, W1, W2, bq, bk, bv,
                                           xbf, wqkv, wob, w1b, w2b, bqkv);
    gemm_bt<0, 128><<<dim3(32, 24), 256, 0, stream>>>(xbf, wqkv, bqkv, nullptr, qkv, NT, 3072, 1024);
    transpose_v<<<dim3(16, 64), 256, 0, stream>>>(qkv, vt);
    flash_attn<<<dim3(64, 8), 512, 0, stream>>>(qkv, vt, maskp, attn);
    // O-proj: split-K=2, raw f32 partials; epilogue folded into ln_fuse<0>
    gemm_bt<3, 128, 2><<<dim3(32, 8, 2), 256, 0, stream>>>(attn, wob, nullptr, nullptr, part, NT, 1024, 1024);
    ln_fuse<0><<<4096, 256, 0, stream>>>(part, query, bo, g1, be1, x1bf, x1f);
    gemm_bt<0, 128><<<dim3(32, 32), 256, 0, stream>>>(x1bf, w1b, b1, nullptr, h1, NT, 4096, 1024);
    // FFN2: split-K=2, raw f32 partials; gelu+res folded into ln_fuse<1>
    gemm_bt<3, 128, 2><<<dim3(32, 8, 2), 256, 0, stream>>>(h1, w2b, nullptr, nullptr, part, NT, 1024, 4096);
    ln_fuse<1><<<4096, 256, 0, stream>>>(part, x1f, b2, g2, be2, nullptr, outf);
}